// Round 1
// baseline (874.427 us; speedup 1.0000x reference)
//
#include <hip/hip_runtime.h>

// Problem constants
#define NB 2
#define NC 64
#define HW 200704          // 448*448
#define CHW 12845056       // 64*HW
#define P2 196
#define NCHUNK 1024
#define NCELL 3136         // 56*56
#define WMN 38416          // 196*196

typedef __attribute__((ext_vector_type(8))) short bfrag;   // 8 bf16 (A/B frag)
typedef __attribute__((ext_vector_type(4))) float ffrag;   // 4 f32  (C/D frag)
typedef __attribute__((ext_vector_type(4))) short short4v;
typedef __attribute__((ext_vector_type(4))) float float4v;

#define MFMA16(A,B,C) __builtin_amdgcn_mfma_f32_16x16x32_bf16(A,B,C,0,0,0)

__device__ __forceinline__ short f2bf(float f) {
  unsigned u = __builtin_bit_cast(unsigned, f);
  u = u + 0x7FFFu + ((u >> 16) & 1u);           // RNE
  return (short)(u >> 16);
}

// ---------------- K1: groupnorm stats (sum,sumsq) + 8x8 avg-pool of x -------
// grid: NB*64*56 blocks of 64 threads. Block = (batch, channel, pool-row).
__global__ __launch_bounds__(64) void k1_stats_pool(
    const float* __restrict__ x, float* __restrict__ xpool, float* __restrict__ stats) {
  int bx = blockIdx.x;
  int batch = bx / (64*56);
  int c = (bx / 56) % 64;
  int pr = bx % 56;
  int l = threadIdx.x;
  const float* xp = x + (size_t)batch*CHW + (size_t)c*HW + pr*8*448;
  float cell = 0.f, s2 = 0.f;
  if (l < 56) {
    #pragma unroll
    for (int r = 0; r < 8; ++r) {
      float4v a = *(const float4v*)(xp + r*448 + l*8);
      float4v b = *(const float4v*)(xp + r*448 + l*8 + 4);
      #pragma unroll
      for (int j = 0; j < 4; ++j) { cell += a[j] + b[j]; s2 += a[j]*a[j] + b[j]*b[j]; }
    }
    xpool[((size_t)batch*64 + c)*NCELL + pr*56 + l] = cell * (1.f/64.f);
  }
  float s1 = (l < 56) ? cell : 0.f;
  #pragma unroll
  for (int m = 1; m < 64; m <<= 1) { s1 += __shfl_xor(s1, m, 64); s2 += __shfl_xor(s2, m, 64); }
  if (l == 0) { atomicAdd(stats + batch*2, s1); atomicAdd(stats + batch*2 + 1, s2); }
}

// ---------------- K2: xn = GN(x); q,k,v = conv1x1 (MFMA) -------------------
// q,k stored pixel-major [pixel][c] bf16; v stored c-major [c][pixel] bf16.
// grid: NB*784 blocks (256 px each) of 256 threads (4 waves).
__global__ __launch_bounds__(256) void k2_qkv(
    const float* __restrict__ x, const float* __restrict__ gnw, const float* __restrict__ gnb,
    const float* __restrict__ qw, const float* __restrict__ qb,
    const float* __restrict__ kw, const float* __restrict__ kb,
    const float* __restrict__ vw, const float* __restrict__ vb,
    const float* __restrict__ stats,
    short* __restrict__ qx, short* __restrict__ kx, short* __restrict__ vnat) {
  __shared__ __attribute__((aligned(16))) short xnt[256*72];  // [px][c] bf16, pitch 72
  int bx = blockIdx.x;
  int batch = bx / 784;
  int px0 = (bx % 784) * 256;
  int t = threadIdx.x;
  float s1 = stats[batch*2], s2 = stats[batch*2+1];
  float mean = s1 * (1.f/CHW);
  float rstd = rsqrtf(s2*(1.f/CHW) - mean*mean + 1e-5f);
  // stage normalized tile, transposed to px-major
  for (int it = 0; it < 64; ++it) {
    float v = x[(size_t)batch*CHW + (size_t)it*HW + px0 + t];
    v = (v - mean) * rstd * gnw[it] + gnb[it];
    xnt[t*72 + it] = f2bf(v);
  }
  __syncthreads();
  int l = t & 63, w = t >> 6, li = l & 15, q_ = l >> 4;
  // B-frags: this wave owns n-tiles w*4 .. w*4+3 (16 px each)
  bfrag bfr[4][2];
  #pragma unroll
  for (int nn = 0; nn < 4; ++nn) {
    int row = (w*4 + nn)*16 + li;
    bfr[nn][0] = *(const bfrag*)(xnt + row*72 + q_*8);
    bfr[nn][1] = *(const bfrag*)(xnt + row*72 + 32 + q_*8);
  }
  const float* Ws[3] = {qw, kw, vw};
  const float* Bs[3] = {qb, kb, vb};
  for (int T = 0; T < 3; ++T) {
    ffrag acc[4][4];
    #pragma unroll
    for (int mt = 0; mt < 4; ++mt) {
      bfrag a0, a1;
      const float* wp = Ws[T] + (mt*16 + li)*64;
      #pragma unroll
      for (int j = 0; j < 8; ++j) { a0[j] = f2bf(wp[q_*8 + j]); a1[j] = f2bf(wp[32 + q_*8 + j]); }
      #pragma unroll
      for (int nn = 0; nn < 4; ++nn) {
        ffrag z = {0.f,0.f,0.f,0.f};
        z = MFMA16(a0, bfr[nn][0], z);
        z = MFMA16(a1, bfr[nn][1], z);
        acc[mt][nn] = z;
      }
    }
    if (T < 2) {
      short* dstb = (T == 0 ? qx : kx) + (size_t)batch*HW*64;
      #pragma unroll
      for (int nn = 0; nn < 4; ++nn) {
        int px = px0 + (w*4 + nn)*16 + li;
        #pragma unroll
        for (int mt = 0; mt < 4; ++mt) {
          float4v bias = *(const float4v*)(Bs[T] + mt*16 + q_*4);
          short4v s;
          #pragma unroll
          for (int r = 0; r < 4; ++r) s[r] = f2bf(acc[mt][nn][r] + bias[r]);
          *(short4v*)(dstb + (size_t)px*64 + mt*16 + q_*4) = s;
        }
      }
    } else {
      #pragma unroll
      for (int nn = 0; nn < 4; ++nn) {
        int px = px0 + (w*4 + nn)*16 + li;
        #pragma unroll
        for (int mt = 0; mt < 4; ++mt) {
          float4v bias = *(const float4v*)(Bs[T] + mt*16 + q_*4);
          #pragma unroll
          for (int r = 0; r < 4; ++r) {
            int c = mt*16 + q_*4 + r;
            vnat[((size_t)batch*64 + c)*HW + px] = f2bf(acc[mt][nn][r] + bias[r]);
          }
        }
      }
    }
  }
}

// ---------------- K2a: pooled qg/kg/vg from pool(x) (linearity) ------------
// qg_t[j][c], kg_t[j][c] bf16; vg[c][j] bf16. grid: NB*49 x 256.
__global__ __launch_bounds__(256) void k2a_pool_qkv(
    const float* __restrict__ xpool, const float* __restrict__ stats,
    const float* __restrict__ gnw, const float* __restrict__ gnb,
    const float* __restrict__ qw, const float* __restrict__ qb,
    const float* __restrict__ kw, const float* __restrict__ kb,
    const float* __restrict__ vw, const float* __restrict__ vb,
    short* __restrict__ qgt, short* __restrict__ kgt, short* __restrict__ vgn) {
  __shared__ float xs[64][64];
  int bx = blockIdx.x;
  int batch = bx / 49;
  int j0 = (bx % 49) * 64;
  int t = threadIdx.x;
  float s1 = stats[batch*2], s2 = stats[batch*2+1];
  float mean = s1 * (1.f/CHW);
  float rstd = rsqrtf(s2*(1.f/CHW) - mean*mean + 1e-5f);
  #pragma unroll
  for (int it = 0; it < 16; ++it) {
    int idx = t + it*256;
    int c = idx >> 6, jl = idx & 63;
    float v = xpool[((size_t)batch*64 + c)*NCELL + j0 + jl];
    xs[c][jl] = (v - mean)*rstd*gnw[c] + gnb[c];
  }
  __syncthreads();
  int jl = t & 63;
  int og = (t >> 6) * 16;
  int j = j0 + jl;
  for (int T = 0; T < 3; ++T) {
    const float* W  = (T==0 ? qw : (T==1 ? kw : vw));
    const float* Bv = (T==0 ? qb : (T==1 ? kb : vb));
    float o16[16];
    #pragma unroll
    for (int oo = 0; oo < 16; ++oo) o16[oo] = Bv[og+oo];
    for (int c = 0; c < 64; ++c) {
      float xv = xs[c][jl];
      #pragma unroll
      for (int oo = 0; oo < 16; ++oo) o16[oo] += W[(og+oo)*64 + c] * xv;
    }
    if (T < 2) {
      short* dst = (T==0 ? qgt : kgt) + ((size_t)batch*NCELL + j)*64 + og;
      #pragma unroll
      for (int oo = 0; oo < 16; oo += 4) {
        short4v s;
        #pragma unroll
        for (int r = 0; r < 4; ++r) s[r] = f2bf(o16[oo+r]);
        *(short4v*)(dst + oo) = s;
      }
    } else {
      #pragma unroll
      for (int oo = 0; oo < 16; ++oo)
        vgn[((size_t)batch*64 + og + oo)*NCELL + j] = f2bf(o16[oo]);
    }
  }
}

// ---------------- K3: wm[p,q] = sum_s qf[s,p] kf[s,q], split-K + atomics ----
// Reduction reordered as sum over (chunk, c); q/k pixel-major gives contiguous
// k-frags. grid: NB*128 blocks (8 chunks = K 512 each) of 512 threads (8 waves).
__global__ __launch_bounds__(512) void k3_wm(
    const short* __restrict__ qx, const short* __restrict__ kx, float* __restrict__ wmacc) {
  int bx = blockIdx.x;
  int batch = bx >> 7;
  int slab = bx & 127;
  int t = threadIdx.x;
  int l = t & 63, w = t >> 6, li = l & 15, q_ = l >> 4;
  int wm_ = w >> 2, wn = w & 3;
  int m0 = wm_ * 7, mcnt = wm_ ? 6 : 7;
  int nt0 = wn ? 4 + (wn-1)*3 : 0, ncnt = wn ? 3 : 4;
  ffrag acc[7][4];
  #pragma unroll
  for (int i = 0; i < 7; ++i)
    #pragma unroll
    for (int j = 0; j < 4; ++j) acc[i][j] = (ffrag){0.f,0.f,0.f,0.f};
  const short* qbase = qx + (size_t)batch*HW*64;
  const short* kbase = kx + (size_t)batch*HW*64;
  for (int c8 = 0; c8 < 8; ++c8) {
    int chunk = slab*8 + c8;
    const short* qc = qbase + (size_t)chunk*P2*64;
    const short* kc = kbase + (size_t)chunk*P2*64;
    #pragma unroll
    for (int ks = 0; ks < 2; ++ks) {
      int koff = ks*32 + q_*8;
      bfrag af[7], bf[4];
      #pragma unroll
      for (int mi = 0; mi < 7; ++mi) if (mi < mcnt)
        af[mi] = *(const bfrag*)(qc + (size_t)((m0+mi)*16 + li)*64 + koff);
      #pragma unroll
      for (int ni = 0; ni < 4; ++ni) if (ni < ncnt)
        bf[ni] = *(const bfrag*)(kc + (size_t)((nt0+ni)*16 + li)*64 + koff);
      #pragma unroll
      for (int mi = 0; mi < 7; ++mi) if (mi < mcnt)
        #pragma unroll
        for (int ni = 0; ni < 4; ++ni) if (ni < ncnt)
          acc[mi][ni] = MFMA16(af[mi], bf[ni], acc[mi][ni]);
    }
  }
  float* wdst = wmacc + (size_t)batch*WMN;
  #pragma unroll
  for (int mi = 0; mi < 7; ++mi) if (mi < mcnt)
    #pragma unroll
    for (int ni = 0; ni < 4; ++ni) if (ni < ncnt) {
      int qcol = (nt0+ni)*16 + li;
      if (qcol < 196)
        #pragma unroll
        for (int r = 0; r < 4; ++r) {
          int prow = (m0+mi)*16 + q_*4 + r;
          if (prow < 196) atomicAdd(wdst + prow*196 + qcol, acc[mi][ni][r]);
        }
    }
}

// ---------------- K4: scale + softmax rows -> P bf16 [208][224] zero-padded -
__global__ __launch_bounds__(64) void k4_softmax(
    const float* __restrict__ wmacc, short* __restrict__ P) {
  int bx = blockIdx.x;         // NB*208
  int batch = bx / 208;
  int p = bx % 208;
  int l = threadIdx.x;
  short* prow = P + ((size_t)batch*208 + p)*224;
  if (p >= 196) { for (int j = l; j < 224; j += 64) prow[j] = 0; return; }
  const float* src = wmacc + (size_t)batch*WMN + p*196;
  float v[4]; float mx = -1e30f;
  #pragma unroll
  for (int i = 0; i < 4; ++i) {
    int q = l + i*64;
    v[i] = (q < 196) ? src[q]*(1.f/256.f) : -1e30f;
    mx = fmaxf(mx, v[i]);
  }
  #pragma unroll
  for (int m = 1; m < 64; m <<= 1) mx = fmaxf(mx, __shfl_xor(mx, m, 64));
  float s = 0.f;
  #pragma unroll
  for (int i = 0; i < 4; ++i) { v[i] = __expf(v[i] - mx); s += v[i]; }
  #pragma unroll
  for (int m = 1; m < 64; m <<= 1) s += __shfl_xor(s, m, 64);
  float inv = 1.f / s;
  #pragma unroll
  for (int i = 0; i < 4; ++i) {
    int q = l + i*64;
    if (q < 224) prow[q] = (q < 196) ? f2bf(v[i]*inv) : (short)0;
  }
}

// ---------------- K5: global pooled attention, flash-style ------------------
// grid NB*49 x 256 (4 waves, one 16-query tile each). hg_t[j][c] fp32 out.
__global__ __launch_bounds__(256) void k5_gattn(
    const short* __restrict__ qgt, const short* __restrict__ kgt,
    const short* __restrict__ vgn, float* __restrict__ hgt) {
  __shared__ __attribute__((aligned(16))) short Pl[4][16][72];
  __shared__ __attribute__((aligned(16))) float alph[4][16];
  __shared__ __attribute__((aligned(16))) float lsum[4][16];
  int bx = blockIdx.x;
  int batch = bx / 49;
  int t = threadIdx.x;
  int w = t >> 6, l = t & 63, li = l & 15, q_ = l >> 4;
  int i0 = (bx % 49)*64 + w*16;
  const short* qg = qgt + (size_t)batch*NCELL*64;
  const short* kg = kgt + (size_t)batch*NCELL*64;
  const short* vg = vgn + (size_t)batch*64*NCELL;
  bfrag bq0 = *(const bfrag*)(qg + (size_t)(i0+li)*64 + q_*8);
  bfrag bq1 = *(const bfrag*)(qg + (size_t)(i0+li)*64 + 32 + q_*8);
  float m_run = -1e30f, l_run = 0.f;
  ffrag oa[4];
  #pragma unroll
  for (int i = 0; i < 4; ++i) oa[i] = (ffrag){0.f,0.f,0.f,0.f};
  for (int jt = 0; jt < 49; ++jt) {
    int j0 = jt*64;
    ffrag st[4];
    #pragma unroll
    for (int mt = 0; mt < 4; ++mt) {        // S^T[j,i]: rows j, cols i
      bfrag a0 = *(const bfrag*)(kg + (size_t)(j0 + mt*16 + li)*64 + q_*8);
      bfrag a1 = *(const bfrag*)(kg + (size_t)(j0 + mt*16 + li)*64 + 32 + q_*8);
      ffrag z = {0.f,0.f,0.f,0.f};
      z = MFMA16(a0, bq0, z);
      z = MFMA16(a1, bq1, z);
      st[mt] = z;
    }
    float mx = -1e30f;
    #pragma unroll
    for (int mt = 0; mt < 4; ++mt)
      #pragma unroll
      for (int r = 0; r < 4; ++r) { st[mt][r] *= 0.125f; mx = fmaxf(mx, st[mt][r]); }
    mx = fmaxf(mx, __shfl_xor(mx, 16, 64));
    mx = fmaxf(mx, __shfl_xor(mx, 32, 64));
    float m_new = fmaxf(m_run, mx);
    float alpha = __expf(m_run - m_new);
    float ps = 0.f;
    short4v pk[4];
    #pragma unroll
    for (int mt = 0; mt < 4; ++mt)
      #pragma unroll
      for (int r = 0; r < 4; ++r) { float e = __expf(st[mt][r] - m_new); ps += e; pk[mt][r] = f2bf(e); }
    ps += __shfl_xor(ps, 16, 64);
    ps += __shfl_xor(ps, 32, 64);
    l_run = l_run*alpha + ps;
    m_run = m_new;
    #pragma unroll
    for (int mt = 0; mt < 4; ++mt) *(short4v*)(&Pl[w][li][mt*16 + q_*4]) = pk[mt];
    alph[w][li] = alpha;
    __syncthreads();
    float4v al = *(const float4v*)(&alph[w][q_*4]);
    #pragma unroll
    for (int nt = 0; nt < 4; ++nt)
      #pragma unroll
      for (int r = 0; r < 4; ++r) oa[nt][r] *= al[r];
    #pragma unroll
    for (int ks = 0; ks < 2; ++ks) {
      bfrag a = *(const bfrag*)(&Pl[w][li][ks*32 + q_*8]);
      #pragma unroll
      for (int nt = 0; nt < 4; ++nt) {
        bfrag b = *(const bfrag*)(vg + (size_t)(nt*16 + li)*NCELL + j0 + ks*32 + q_*8);
        oa[nt] = MFMA16(a, b, oa[nt]);
      }
    }
    __syncthreads();
  }
  lsum[w][li] = l_run;
  __syncthreads();
  float4v lv = *(const float4v*)(&lsum[w][q_*4]);
  float* dst = hgt + (size_t)batch*NCELL*64;
  #pragma unroll
  for (int r = 0; r < 4; ++r) {
    float inv = 1.f / lv[r];
    int i = i0 + q_*4 + r;
    #pragma unroll
    for (int nt = 0; nt < 4; ++nt) dst[(size_t)i*64 + nt*16 + li] = oa[nt][r] * inv;
  }
}

// ---------------- K6: per-chunk hp MFMA + combine hg + proj MFMA + residual -
// grid NB*1024 x 256 (4 waves).
__global__ __launch_bounds__(256) void k6_hp_proj(
    const short* __restrict__ vnat, const short* __restrict__ P,
    const float* __restrict__ hgt, const float* __restrict__ projw,
    const float* __restrict__ x, float* __restrict__ out) {
  __shared__ __attribute__((aligned(16))) short vch[64*224];   // [c][p] pitch 224
  __shared__ __attribute__((aligned(16))) short hl[208*72];    // [p'][c] pitch 72
  int bx = blockIdx.x;
  int batch = bx >> 10;
  int chunk = bx & 1023;
  int t = threadIdx.x;
  const short* vsrc = vnat + (size_t)batch*64*HW + chunk*P2;
  for (int idx = t; idx < 3136; idx += 256) {       // 64 rows x 49 short4
    int c = idx / 49, po = idx % 49;
    *(short4v*)(vch + c*224 + po*4) = *(const short4v*)(vsrc + (size_t)c*HW + po*4);
  }
  for (int idx = t; idx < 448; idx += 256) {        // zero pad cols 196..223
    int c = idx / 7, po = idx % 7;
    *(short4v*)(vch + c*224 + 196 + po*4) = (short4v){0,0,0,0};
  }
  __syncthreads();
  int l = t & 63, w = t >> 6, li = l & 15, q_ = l >> 4;
  int nt0 = w ? 4 + (w-1)*3 : 0;
  int ncnt = w ? 3 : 4;
  const short* Pb = P + (size_t)batch*208*224;
  ffrag acc[4][4];
  #pragma unroll
  for (int i = 0; i < 4; ++i)
    #pragma unroll
    for (int j = 0; j < 4; ++j) acc[i][j] = (ffrag){0.f,0.f,0.f,0.f};
  #pragma unroll
  for (int ks = 0; ks < 7; ++ks) {
    int koff = ks*32 + q_*8;
    bfrag av[4];
    #pragma unroll
    for (int mt = 0; mt < 4; ++mt) av[mt] = *(const bfrag*)(vch + (mt*16 + li)*224 + koff);
    #pragma unroll
    for (int ni = 0; ni < 4; ++ni) if (ni < ncnt) {
      bfrag bp = *(const bfrag*)(Pb + (size_t)((nt0+ni)*16 + li)*224 + koff);
      #pragma unroll
      for (int mt = 0; mt < 4; ++mt) acc[mt][ni] = MFMA16(av[mt], bp, acc[mt][ni]);
    }
  }
  const float* hgb = hgt + (size_t)batch*NCELL*64;
  #pragma unroll
  for (int ni = 0; ni < 4; ++ni) if (ni < ncnt) {
    int pp = (nt0+ni)*16 + li;
    if (pp < 196) {
      int g = chunk*P2 + pp;
      int hh = g / 448, ww_ = g % 448;
      int cell = (hh >> 3)*56 + (ww_ >> 3);
      #pragma unroll
      for (int mt = 0; mt < 4; ++mt) {
        float4v hgv = *(const float4v*)(hgb + (size_t)cell*64 + mt*16 + q_*4);
        short4v s;
        #pragma unroll
        for (int r = 0; r < 4; ++r) s[r] = f2bf(0.75f*acc[mt][ni][r] + 0.25f*hgv[r]);
        *(short4v*)(hl + pp*72 + mt*16 + q_*4) = s;
      }
    }
  }
  __syncthreads();
  ffrag acc2[4][4];
  #pragma unroll
  for (int i = 0; i < 4; ++i)
    #pragma unroll
    for (int j = 0; j < 4; ++j) acc2[i][j] = (ffrag){0.f,0.f,0.f,0.f};
  #pragma unroll
  for (int ks = 0; ks < 2; ++ks) {
    bfrag aw[4];
    #pragma unroll
    for (int mt = 0; mt < 4; ++mt) {
      const float* wp = projw + (mt*16 + li)*64 + ks*32 + q_*8;
      #pragma unroll
      for (int j = 0; j < 8; ++j) aw[mt][j] = f2bf(wp[j]);
    }
    #pragma unroll
    for (int ni = 0; ni < 4; ++ni) if (ni < ncnt) {
      bfrag bh = *(const bfrag*)(hl + ((nt0+ni)*16 + li)*72 + ks*32 + q_*8);
      #pragma unroll
      for (int mt = 0; mt < 4; ++mt) acc2[mt][ni] = MFMA16(aw[mt], bh, acc2[mt][ni]);
    }
  }
  const float* xb = x + (size_t)batch*CHW;
  float* ob = out + (size_t)batch*CHW;
  #pragma unroll
  for (int ni = 0; ni < 4; ++ni) if (ni < ncnt) {
    int pp = (nt0+ni)*16 + li;
    if (pp < 196) {
      int g = chunk*P2 + pp;
      #pragma unroll
      for (int mt = 0; mt < 4; ++mt)
        #pragma unroll
        for (int r = 0; r < 4; ++r) {
          int o = mt*16 + q_*4 + r;
          ob[(size_t)o*HW + g] = xb[(size_t)o*HW + g] + acc2[mt][ni][r];
        }
    }
  }
}

// ---------------- launch ----------------------------------------------------
extern "C" void kernel_launch(void* const* d_in, const int* in_sizes, int n_in,
                              void* d_out, int out_size, void* d_ws, size_t ws_size,
                              hipStream_t stream) {
  (void)in_sizes; (void)n_in; (void)out_size; (void)ws_size;
  const float* x   = (const float*)d_in[0];
  const float* gnw = (const float*)d_in[1];
  const float* gnb = (const float*)d_in[2];
  const float* qw  = (const float*)d_in[3];
  const float* qb  = (const float*)d_in[4];
  const float* kw  = (const float*)d_in[5];
  const float* kb  = (const float*)d_in[6];
  const float* vw  = (const float*)d_in[7];
  const float* vb  = (const float*)d_in[8];
  const float* pw  = (const float*)d_in[9];
  float* out = (float*)d_out;
  char* ws = (char*)d_ws;

  // ws layout (bytes), all 256-aligned; total ~160.3 MB
  short* qx    = (short*)(ws + 0);            // 51,380,224  q pixel-major bf16
  short* kx    = (short*)(ws + 51380224);     // 51,380,224
  short* vnat  = (short*)(ws + 102760448);    // 51,380,224  v c-major bf16
  float* xpool = (float*)(ws + 154140672);    //  1,605,632
  short* qgt   = (short*)(ws + 155746304);    //    802,816
  short* kgt   = (short*)(ws + 156549120);    //    802,816
  short* vgn   = (short*)(ws + 157351936);    //    802,816
  float* hgt   = (float*)(ws + 158154752);    //  1,605,632
  short* P     = (short*)(ws + 159760384);    //    186,368  [b][208][224] bf16
  float* wmacc = (float*)(ws + 159946752);    //    307,328  fp32 atomics
  float* stats = (float*)(ws + 160254080);    //         16

  hipMemsetAsync(ws + 159946752, 0, 307328 + 16, stream);   // wmacc + stats
  k1_stats_pool<<<dim3(NB*64*56), dim3(64),  0, stream>>>(x, xpool, stats);
  k2_qkv       <<<dim3(NB*784),   dim3(256), 0, stream>>>(x, gnw, gnb, qw, qb, kw, kb, vw, vb, stats, qx, kx, vnat);
  k2a_pool_qkv <<<dim3(NB*49),    dim3(256), 0, stream>>>(xpool, stats, gnw, gnb, qw, qb, kw, kb, vw, vb, qgt, kgt, vgn);
  k3_wm        <<<dim3(NB*128),   dim3(512), 0, stream>>>(qx, kx, wmacc);
  k4_softmax   <<<dim3(NB*208),   dim3(64),  0, stream>>>(wmacc, P);
  k5_gattn     <<<dim3(NB*49),    dim3(256), 0, stream>>>(qgt, kgt, vgn, hgt);
  k6_hp_proj   <<<dim3(NB*1024),  dim3(256), 0, stream>>>(vnat, P, hgt, pw, x, out);
}

// Round 2
// 690.140 us; speedup vs baseline: 1.2670x; 1.2670x over previous
//
#include <hip/hip_runtime.h>

// Problem constants
#define NB 2
#define NC 64
#define HW 200704          // 448*448
#define CHW 12845056       // 64*HW
#define P2 196
#define NCHUNK 1024
#define NCELL 3136         // 56*56
#define WMN 38416          // 196*196

typedef __attribute__((ext_vector_type(8))) short bfrag;   // 8 bf16 (A/B frag)
typedef __attribute__((ext_vector_type(4))) float ffrag;   // 4 f32  (C/D frag)
typedef __attribute__((ext_vector_type(4))) short short4v;
typedef __attribute__((ext_vector_type(4))) float float4v;

#define MFMA16(A,B,C) __builtin_amdgcn_mfma_f32_16x16x32_bf16(A,B,C,0,0,0)

__device__ __forceinline__ short f2bf(float f) {
  unsigned u = __builtin_bit_cast(unsigned, f);
  u = u + 0x7FFFu + ((u >> 16) & 1u);           // RNE
  return (short)(u >> 16);
}

// ---------------- K1: groupnorm partial stats + 8x8 avg-pool of x ----------
// grid: NB*64*56 blocks of 64 threads. Block = (batch, channel, pool-row).
// Writes per-block (s1,s2) partials -- NO same-address atomics (R1: 194us of
// atomic serialization on 4 addresses).
__global__ __launch_bounds__(64) void k1_stats_pool(
    const float* __restrict__ x, float* __restrict__ xpool, float* __restrict__ partials) {
  int bx = blockIdx.x;
  int batch = bx / (64*56);
  int c = (bx / 56) % 64;
  int pr = bx % 56;
  int l = threadIdx.x;
  const float* xp = x + (size_t)batch*CHW + (size_t)c*HW + pr*8*448;
  float cell = 0.f, s2 = 0.f;
  if (l < 56) {
    #pragma unroll
    for (int r = 0; r < 8; ++r) {
      float4v a = *(const float4v*)(xp + r*448 + l*8);
      float4v b = *(const float4v*)(xp + r*448 + l*8 + 4);
      #pragma unroll
      for (int j = 0; j < 4; ++j) { cell += a[j] + b[j]; s2 += a[j]*a[j] + b[j]*b[j]; }
    }
    xpool[((size_t)batch*64 + c)*NCELL + pr*56 + l] = cell * (1.f/64.f);
  }
  float s1 = (l < 56) ? cell : 0.f;
  #pragma unroll
  for (int m = 1; m < 64; m <<= 1) { s1 += __shfl_xor(s1, m, 64); s2 += __shfl_xor(s2, m, 64); }
  if (l == 0) { partials[bx*2] = s1; partials[bx*2 + 1] = s2; }
}

// ---------------- K1b: reduce 7168 partial pairs -> stats[4] ---------------
__global__ __launch_bounds__(256) void k1b_reduce(
    const float* __restrict__ partials, float* __restrict__ stats) {
  __shared__ float red[2][256];
  int t = threadIdx.x;
  for (int b = 0; b < NB; ++b) {
    float s1 = 0.f, s2 = 0.f;
    for (int i = t; i < 3584; i += 256) {
      s1 += partials[(b*3584 + i)*2];
      s2 += partials[(b*3584 + i)*2 + 1];
    }
    red[0][t] = s1; red[1][t] = s2;
    __syncthreads();
    for (int m = 128; m > 0; m >>= 1) {
      if (t < m) { red[0][t] += red[0][t+m]; red[1][t] += red[1][t+m]; }
      __syncthreads();
    }
    if (t == 0) { stats[b*2] = red[0][0]; stats[b*2+1] = red[1][0]; }
    __syncthreads();
  }
}

// ---------------- K2: xn = GN(x); q,k,v = conv1x1 (MFMA) -------------------
// q,k stored pixel-major [pixel][c] bf16; v stored c-major [c][pixel] bf16.
// grid: NB*784 blocks (256 px each) of 256 threads (4 waves).
__global__ __launch_bounds__(256) void k2_qkv(
    const float* __restrict__ x, const float* __restrict__ gnw, const float* __restrict__ gnb,
    const float* __restrict__ qw, const float* __restrict__ qb,
    const float* __restrict__ kw, const float* __restrict__ kb,
    const float* __restrict__ vw, const float* __restrict__ vb,
    const float* __restrict__ stats,
    short* __restrict__ qx, short* __restrict__ kx, short* __restrict__ vnat) {
  __shared__ __attribute__((aligned(16))) short xnt[256*72];  // [px][c] bf16, pitch 72
  int bx = blockIdx.x;
  int batch = bx / 784;
  int px0 = (bx % 784) * 256;
  int t = threadIdx.x;
  float s1 = stats[batch*2], s2 = stats[batch*2+1];
  float mean = s1 * (1.f/CHW);
  float rstd = rsqrtf(s2*(1.f/CHW) - mean*mean + 1e-5f);
  // stage normalized tile, transposed to px-major; 4 channels/iter -> b64 LDS writes
  for (int it = 0; it < 64; it += 4) {
    float vv[4];
    #pragma unroll
    for (int r = 0; r < 4; ++r) {
      float v = x[(size_t)batch*CHW + (size_t)(it+r)*HW + px0 + t];
      vv[r] = (v - mean) * rstd * gnw[it+r] + gnb[it+r];
    }
    short4v s;
    #pragma unroll
    for (int r = 0; r < 4; ++r) s[r] = f2bf(vv[r]);
    *(short4v*)(xnt + t*72 + it) = s;
  }
  __syncthreads();
  int l = t & 63, w = t >> 6, li = l & 15, q_ = l >> 4;
  // B-frags: this wave owns n-tiles w*4 .. w*4+3 (16 px each)
  bfrag bfr[4][2];
  #pragma unroll
  for (int nn = 0; nn < 4; ++nn) {
    int row = (w*4 + nn)*16 + li;
    bfr[nn][0] = *(const bfrag*)(xnt + row*72 + q_*8);
    bfr[nn][1] = *(const bfrag*)(xnt + row*72 + 32 + q_*8);
  }
  const float* Ws[3] = {qw, kw, vw};
  const float* Bs[3] = {qb, kb, vb};
  for (int T = 0; T < 3; ++T) {
    ffrag acc[4][4];
    #pragma unroll
    for (int mt = 0; mt < 4; ++mt) {
      bfrag a0, a1;
      const float* wp = Ws[T] + (mt*16 + li)*64;
      #pragma unroll
      for (int j = 0; j < 8; ++j) { a0[j] = f2bf(wp[q_*8 + j]); a1[j] = f2bf(wp[32 + q_*8 + j]); }
      #pragma unroll
      for (int nn = 0; nn < 4; ++nn) {
        ffrag z = {0.f,0.f,0.f,0.f};
        z = MFMA16(a0, bfr[nn][0], z);
        z = MFMA16(a1, bfr[nn][1], z);
        acc[mt][nn] = z;
      }
    }
    if (T < 2) {
      short* dstb = (T == 0 ? qx : kx) + (size_t)batch*HW*64;
      #pragma unroll
      for (int nn = 0; nn < 4; ++nn) {
        int px = px0 + (w*4 + nn)*16 + li;
        #pragma unroll
        for (int mt = 0; mt < 4; ++mt) {
          float4v bias = *(const float4v*)(Bs[T] + mt*16 + q_*4);
          short4v s;
          #pragma unroll
          for (int r = 0; r < 4; ++r) s[r] = f2bf(acc[mt][nn][r] + bias[r]);
          *(short4v*)(dstb + (size_t)px*64 + mt*16 + q_*4) = s;
        }
      }
    } else {
      #pragma unroll
      for (int nn = 0; nn < 4; ++nn) {
        int px = px0 + (w*4 + nn)*16 + li;
        #pragma unroll
        for (int mt = 0; mt < 4; ++mt) {
          float4v bias = *(const float4v*)(Bs[T] + mt*16 + q_*4);
          #pragma unroll
          for (int r = 0; r < 4; ++r) {
            int c = mt*16 + q_*4 + r;
            vnat[((size_t)batch*64 + c)*HW + px] = f2bf(acc[mt][nn][r] + bias[r]);
          }
        }
      }
    }
  }
}

// ---------------- K2a: pooled qg/kg/vg from pool(x) (linearity) ------------
// qg_t[j][c], kg_t[j][c] bf16; vg[c][j] bf16. grid: NB*49 x 256.
__global__ __launch_bounds__(256) void k2a_pool_qkv(
    const float* __restrict__ xpool, const float* __restrict__ stats,
    const float* __restrict__ gnw, const float* __restrict__ gnb,
    const float* __restrict__ qw, const float* __restrict__ qb,
    const float* __restrict__ kw, const float* __restrict__ kb,
    const float* __restrict__ vw, const float* __restrict__ vb,
    short* __restrict__ qgt, short* __restrict__ kgt, short* __restrict__ vgn) {
  __shared__ float xs[64][64];
  int bx = blockIdx.x;
  int batch = bx / 49;
  int j0 = (bx % 49) * 64;
  int t = threadIdx.x;
  float s1 = stats[batch*2], s2 = stats[batch*2+1];
  float mean = s1 * (1.f/CHW);
  float rstd = rsqrtf(s2*(1.f/CHW) - mean*mean + 1e-5f);
  #pragma unroll
  for (int it = 0; it < 16; ++it) {
    int idx = t + it*256;
    int c = idx >> 6, jl = idx & 63;
    float v = xpool[((size_t)batch*64 + c)*NCELL + j0 + jl];
    xs[c][jl] = (v - mean)*rstd*gnw[c] + gnb[c];
  }
  __syncthreads();
  int jl = t & 63;
  int og = (t >> 6) * 16;
  int j = j0 + jl;
  for (int T = 0; T < 3; ++T) {
    const float* W  = (T==0 ? qw : (T==1 ? kw : vw));
    const float* Bv = (T==0 ? qb : (T==1 ? kb : vb));
    float o16[16];
    #pragma unroll
    for (int oo = 0; oo < 16; ++oo) o16[oo] = Bv[og+oo];
    for (int c = 0; c < 64; ++c) {
      float xv = xs[c][jl];
      #pragma unroll
      for (int oo = 0; oo < 16; ++oo) o16[oo] += W[(og+oo)*64 + c] * xv;
    }
    if (T < 2) {
      short* dst = (T==0 ? qgt : kgt) + ((size_t)batch*NCELL + j)*64 + og;
      #pragma unroll
      for (int oo = 0; oo < 16; oo += 4) {
        short4v s;
        #pragma unroll
        for (int r = 0; r < 4; ++r) s[r] = f2bf(o16[oo+r]);
        *(short4v*)(dst + oo) = s;
      }
    } else {
      #pragma unroll
      for (int oo = 0; oo < 16; ++oo)
        vgn[((size_t)batch*64 + og + oo)*NCELL + j] = f2bf(o16[oo]);
    }
  }
}

// ---------------- K3: wm[p,q] = sum_s qf[s,p] kf[s,q], split-K + atomics ----
// Reduction reordered as sum over (chunk, c); q/k pixel-major gives contiguous
// k-frags. grid: NB*64 blocks (16 chunks = K 1024 each) of 512 threads.
__global__ __launch_bounds__(512) void k3_wm(
    const short* __restrict__ qx, const short* __restrict__ kx, float* __restrict__ wmacc) {
  int bx = blockIdx.x;
  int batch = bx >> 6;
  int slab = bx & 63;
  int t = threadIdx.x;
  int l = t & 63, w = t >> 6, li = l & 15, q_ = l >> 4;
  int wm_ = w >> 2, wn = w & 3;
  int m0 = wm_ * 7, mcnt = wm_ ? 6 : 7;
  int nt0 = wn ? 4 + (wn-1)*3 : 0, ncnt = wn ? 3 : 4;
  ffrag acc[7][4];
  #pragma unroll
  for (int i = 0; i < 7; ++i)
    #pragma unroll
    for (int j = 0; j < 4; ++j) acc[i][j] = (ffrag){0.f,0.f,0.f,0.f};
  const short* qbase = qx + (size_t)batch*HW*64;
  const short* kbase = kx + (size_t)batch*HW*64;
  for (int c8 = 0; c8 < 16; ++c8) {
    int chunk = slab*16 + c8;
    const short* qc = qbase + (size_t)chunk*P2*64;
    const short* kc = kbase + (size_t)chunk*P2*64;
    #pragma unroll
    for (int ks = 0; ks < 2; ++ks) {
      int koff = ks*32 + q_*8;
      bfrag af[7], bf[4];
      #pragma unroll
      for (int mi = 0; mi < 7; ++mi) if (mi < mcnt)
        af[mi] = *(const bfrag*)(qc + (size_t)((m0+mi)*16 + li)*64 + koff);
      #pragma unroll
      for (int ni = 0; ni < 4; ++ni) if (ni < ncnt)
        bf[ni] = *(const bfrag*)(kc + (size_t)((nt0+ni)*16 + li)*64 + koff);
      #pragma unroll
      for (int mi = 0; mi < 7; ++mi) if (mi < mcnt)
        #pragma unroll
        for (int ni = 0; ni < 4; ++ni) if (ni < ncnt)
          acc[mi][ni] = MFMA16(af[mi], bf[ni], acc[mi][ni]);
    }
  }
  float* wdst = wmacc + (size_t)batch*WMN;
  #pragma unroll
  for (int mi = 0; mi < 7; ++mi) if (mi < mcnt)
    #pragma unroll
    for (int ni = 0; ni < 4; ++ni) if (ni < ncnt) {
      int qcol = (nt0+ni)*16 + li;
      if (qcol < 196)
        #pragma unroll
        for (int r = 0; r < 4; ++r) {
          int prow = (m0+mi)*16 + q_*4 + r;
          if (prow < 196) atomicAdd(wdst + prow*196 + qcol, acc[mi][ni][r]);
        }
    }
}

// ---------------- K4: scale + softmax rows -> P bf16 [208][224] zero-padded -
__global__ __launch_bounds__(64) void k4_softmax(
    const float* __restrict__ wmacc, short* __restrict__ P) {
  int bx = blockIdx.x;         // NB*208
  int batch = bx / 208;
  int p = bx % 208;
  int l = threadIdx.x;
  short* prow = P + ((size_t)batch*208 + p)*224;
  if (p >= 196) { for (int j = l; j < 224; j += 64) prow[j] = 0; return; }
  const float* src = wmacc + (size_t)batch*WMN + p*196;
  float v[4]; float mx = -1e30f;
  #pragma unroll
  for (int i = 0; i < 4; ++i) {
    int q = l + i*64;
    v[i] = (q < 196) ? src[q]*(1.f/256.f) : -1e30f;
    mx = fmaxf(mx, v[i]);
  }
  #pragma unroll
  for (int m = 1; m < 64; m <<= 1) mx = fmaxf(mx, __shfl_xor(mx, m, 64));
  float s = 0.f;
  #pragma unroll
  for (int i = 0; i < 4; ++i) { v[i] = __expf(v[i] - mx); s += v[i]; }
  #pragma unroll
  for (int m = 1; m < 64; m <<= 1) s += __shfl_xor(s, m, 64);
  float inv = 1.f / s;
  #pragma unroll
  for (int i = 0; i < 4; ++i) {
    int q = l + i*64;
    if (q < 224) prow[q] = (q < 196) ? f2bf(v[i]*inv) : (short)0;
  }
}

// ---------------- K5: global pooled attention, flash-style ------------------
// grid NB*49 x 256 (4 waves, one 16-query tile each). hg_t[j][c] fp32 out.
__global__ __launch_bounds__(256) void k5_gattn(
    const short* __restrict__ qgt, const short* __restrict__ kgt,
    const short* __restrict__ vgn, float* __restrict__ hgt) {
  __shared__ __attribute__((aligned(16))) short Pl[4][16][72];
  __shared__ __attribute__((aligned(16))) float alph[4][16];
  __shared__ __attribute__((aligned(16))) float lsum[4][16];
  int bx = blockIdx.x;
  int batch = bx / 49;
  int t = threadIdx.x;
  int w = t >> 6, l = t & 63, li = l & 15, q_ = l >> 4;
  int i0 = (bx % 49)*64 + w*16;
  const short* qg = qgt + (size_t)batch*NCELL*64;
  const short* kg = kgt + (size_t)batch*NCELL*64;
  const short* vg = vgn + (size_t)batch*64*NCELL;
  bfrag bq0 = *(const bfrag*)(qg + (size_t)(i0+li)*64 + q_*8);
  bfrag bq1 = *(const bfrag*)(qg + (size_t)(i0+li)*64 + 32 + q_*8);
  float m_run = -1e30f, l_run = 0.f;
  ffrag oa[4];
  #pragma unroll
  for (int i = 0; i < 4; ++i) oa[i] = (ffrag){0.f,0.f,0.f,0.f};
  for (int jt = 0; jt < 49; ++jt) {
    int j0 = jt*64;
    ffrag st[4];
    #pragma unroll
    for (int mt = 0; mt < 4; ++mt) {        // S^T[j,i]: rows j, cols i
      bfrag a0 = *(const bfrag*)(kg + (size_t)(j0 + mt*16 + li)*64 + q_*8);
      bfrag a1 = *(const bfrag*)(kg + (size_t)(j0 + mt*16 + li)*64 + 32 + q_*8);
      ffrag z = {0.f,0.f,0.f,0.f};
      z = MFMA16(a0, bq0, z);
      z = MFMA16(a1, bq1, z);
      st[mt] = z;
    }
    float mx = -1e30f;
    #pragma unroll
    for (int mt = 0; mt < 4; ++mt)
      #pragma unroll
      for (int r = 0; r < 4; ++r) { st[mt][r] *= 0.125f; mx = fmaxf(mx, st[mt][r]); }
    mx = fmaxf(mx, __shfl_xor(mx, 16, 64));
    mx = fmaxf(mx, __shfl_xor(mx, 32, 64));
    float m_new = fmaxf(m_run, mx);
    float alpha = __expf(m_run - m_new);
    float ps = 0.f;
    short4v pk[4];
    #pragma unroll
    for (int mt = 0; mt < 4; ++mt)
      #pragma unroll
      for (int r = 0; r < 4; ++r) { float e = __expf(st[mt][r] - m_new); ps += e; pk[mt][r] = f2bf(e); }
    ps += __shfl_xor(ps, 16, 64);
    ps += __shfl_xor(ps, 32, 64);
    l_run = l_run*alpha + ps;
    m_run = m_new;
    #pragma unroll
    for (int mt = 0; mt < 4; ++mt) *(short4v*)(&Pl[w][li][mt*16 + q_*4]) = pk[mt];
    alph[w][li] = alpha;
    __syncthreads();
    float4v al = *(const float4v*)(&alph[w][q_*4]);
    #pragma unroll
    for (int nt = 0; nt < 4; ++nt)
      #pragma unroll
      for (int r = 0; r < 4; ++r) oa[nt][r] *= al[r];
    #pragma unroll
    for (int ks = 0; ks < 2; ++ks) {
      bfrag a = *(const bfrag*)(&Pl[w][li][ks*32 + q_*8]);
      #pragma unroll
      for (int nt = 0; nt < 4; ++nt) {
        bfrag b = *(const bfrag*)(vg + (size_t)(nt*16 + li)*NCELL + j0 + ks*32 + q_*8);
        oa[nt] = MFMA16(a, b, oa[nt]);
      }
    }
    __syncthreads();
  }
  lsum[w][li] = l_run;
  __syncthreads();
  float4v lv = *(const float4v*)(&lsum[w][q_*4]);
  float* dst = hgt + (size_t)batch*NCELL*64;
  #pragma unroll
  for (int r = 0; r < 4; ++r) {
    float inv = 1.f / lv[r];
    int i = i0 + q_*4 + r;
    #pragma unroll
    for (int nt = 0; nt < 4; ++nt) dst[(size_t)i*64 + nt*16 + li] = oa[nt][r] * inv;
  }
}

// ---------------- K6: per-chunk hp MFMA + combine hg + proj MFMA + residual -
// grid NB*1024 x 256 (4 waves).
__global__ __launch_bounds__(256) void k6_hp_proj(
    const short* __restrict__ vnat, const short* __restrict__ P,
    const float* __restrict__ hgt, const float* __restrict__ projw,
    const float* __restrict__ x, float* __restrict__ out) {
  __shared__ __attribute__((aligned(16))) short vch[64*224];   // [c][p] pitch 224
  __shared__ __attribute__((aligned(16))) short hl[208*72];    // [p'][c] pitch 72
  int bx = blockIdx.x;
  int batch = bx >> 10;
  int chunk = bx & 1023;
  int t = threadIdx.x;
  const short* vsrc = vnat + (size_t)batch*64*HW + chunk*P2;
  for (int idx = t; idx < 3136; idx += 256) {       // 64 rows x 49 short4
    int c = idx / 49, po = idx % 49;
    *(short4v*)(vch + c*224 + po*4) = *(const short4v*)(vsrc + (size_t)c*HW + po*4);
  }
  for (int idx = t; idx < 448; idx += 256) {        // zero pad cols 196..223
    int c = idx / 7, po = idx % 7;
    *(short4v*)(vch + c*224 + 196 + po*4) = (short4v){0,0,0,0};
  }
  __syncthreads();
  int l = t & 63, w = t >> 6, li = l & 15, q_ = l >> 4;
  int nt0 = w ? 4 + (w-1)*3 : 0;
  int ncnt = w ? 3 : 4;
  const short* Pb = P + (size_t)batch*208*224;
  ffrag acc[4][4];
  #pragma unroll
  for (int i = 0; i < 4; ++i)
    #pragma unroll
    for (int j = 0; j < 4; ++j) acc[i][j] = (ffrag){0.f,0.f,0.f,0.f};
  #pragma unroll
  for (int ks = 0; ks < 7; ++ks) {
    int koff = ks*32 + q_*8;
    bfrag av[4];
    #pragma unroll
    for (int mt = 0; mt < 4; ++mt) av[mt] = *(const bfrag*)(vch + (mt*16 + li)*224 + koff);
    #pragma unroll
    for (int ni = 0; ni < 4; ++ni) if (ni < ncnt) {
      bfrag bp = *(const bfrag*)(Pb + (size_t)((nt0+ni)*16 + li)*224 + koff);
      #pragma unroll
      for (int mt = 0; mt < 4; ++mt) acc[mt][ni] = MFMA16(av[mt], bp, acc[mt][ni]);
    }
  }
  const float* hgb = hgt + (size_t)batch*NCELL*64;
  #pragma unroll
  for (int ni = 0; ni < 4; ++ni) if (ni < ncnt) {
    int pp = (nt0+ni)*16 + li;
    if (pp < 196) {
      int g = chunk*P2 + pp;
      int hh = g / 448, ww_ = g % 448;
      int cell = (hh >> 3)*56 + (ww_ >> 3);
      #pragma unroll
      for (int mt = 0; mt < 4; ++mt) {
        float4v hgv = *(const float4v*)(hgb + (size_t)cell*64 + mt*16 + q_*4);
        short4v s;
        #pragma unroll
        for (int r = 0; r < 4; ++r) s[r] = f2bf(0.75f*acc[mt][ni][r] + 0.25f*hgv[r]);
        *(short4v*)(hl + pp*72 + mt*16 + q_*4) = s;
      }
    }
  }
  __syncthreads();
  ffrag acc2[4][4];
  #pragma unroll
  for (int i = 0; i < 4; ++i)
    #pragma unroll
    for (int j = 0; j < 4; ++j) acc2[i][j] = (ffrag){0.f,0.f,0.f,0.f};
  #pragma unroll
  for (int ks = 0; ks < 2; ++ks) {
    bfrag aw[4];
    #pragma unroll
    for (int mt = 0; mt < 4; ++mt) {
      const float* wp = projw + (mt*16 + li)*64 + ks*32 + q_*8;
      #pragma unroll
      for (int j = 0; j < 8; ++j) aw[mt][j] = f2bf(wp[j]);
    }
    #pragma unroll
    for (int ni = 0; ni < 4; ++ni) if (ni < ncnt) {
      bfrag bh = *(const bfrag*)(hl + ((nt0+ni)*16 + li)*72 + ks*32 + q_*8);
      #pragma unroll
      for (int mt = 0; mt < 4; ++mt) acc2[mt][ni] = MFMA16(aw[mt], bh, acc2[mt][ni]);
    }
  }
  const float* xb = x + (size_t)batch*CHW;
  float* ob = out + (size_t)batch*CHW;
  #pragma unroll
  for (int ni = 0; ni < 4; ++ni) if (ni < ncnt) {
    int pp = (nt0+ni)*16 + li;
    if (pp < 196) {
      int g = chunk*P2 + pp;
      #pragma unroll
      for (int mt = 0; mt < 4; ++mt)
        #pragma unroll
        for (int r = 0; r < 4; ++r) {
          int o = mt*16 + q_*4 + r;
          ob[(size_t)o*HW + g] = xb[(size_t)o*HW + g] + acc2[mt][ni][r];
        }
    }
  }
}

// ---------------- launch ----------------------------------------------------
extern "C" void kernel_launch(void* const* d_in, const int* in_sizes, int n_in,
                              void* d_out, int out_size, void* d_ws, size_t ws_size,
                              hipStream_t stream) {
  (void)in_sizes; (void)n_in; (void)out_size; (void)ws_size;
  const float* x   = (const float*)d_in[0];
  const float* gnw = (const float*)d_in[1];
  const float* gnb = (const float*)d_in[2];
  const float* qw  = (const float*)d_in[3];
  const float* qb  = (const float*)d_in[4];
  const float* kw  = (const float*)d_in[5];
  const float* kb  = (const float*)d_in[6];
  const float* vw  = (const float*)d_in[7];
  const float* vb  = (const float*)d_in[8];
  const float* pw  = (const float*)d_in[9];
  float* out = (float*)d_out;
  char* ws = (char*)d_ws;

  // ws layout (bytes), all 256-aligned; total ~160.3 MB
  short* qx    = (short*)(ws + 0);            // 51,380,224  q pixel-major bf16
  short* kx    = (short*)(ws + 51380224);     // 51,380,224
  short* vnat  = (short*)(ws + 102760448);    // 51,380,224  v c-major bf16
  float* xpool = (float*)(ws + 154140672);    //  1,605,632
  short* qgt   = (short*)(ws + 155746304);    //    802,816
  short* kgt   = (short*)(ws + 156549120);    //    802,816
  short* vgn   = (short*)(ws + 157351936);    //    802,816
  float* hgt   = (float*)(ws + 158154752);    //  1,605,632
  short* P     = (short*)(ws + 159760384);    //    186,368  [b][208][224] bf16
  float* wmacc = (float*)(ws + 159946752);    //    307,328  fp32 atomics
  float* stats = (float*)(ws + 160254080);    //         16
  // stats partials overlaid on P (7168*2*4 = 57,344 B); k1 writes, k1b reads,
  // then k4 overwrites P later -- no lifetime conflict.
  float* partials = (float*)(ws + 159760384);

  hipMemsetAsync(ws + 159946752, 0, 307328, stream);   // wmacc only
  k1_stats_pool<<<dim3(NB*64*56), dim3(64),  0, stream>>>(x, xpool, partials);
  k1b_reduce   <<<dim3(1),        dim3(256), 0, stream>>>(partials, stats);
  k2_qkv       <<<dim3(NB*784),   dim3(256), 0, stream>>>(x, gnw, gnb, qw, qb, kw, kb, vw, vb, stats, qx, kx, vnat);
  k2a_pool_qkv <<<dim3(NB*49),    dim3(256), 0, stream>>>(xpool, stats, gnw, gnb, qw, qb, kw, kb, vw, vb, qgt, kgt, vgn);
  k3_wm        <<<dim3(NB*64),    dim3(512), 0, stream>>>(qx, kx, wmacc);
  k4_softmax   <<<dim3(NB*208),   dim3(64),  0, stream>>>(wmacc, P);
  k5_gattn     <<<dim3(NB*49),    dim3(256), 0, stream>>>(qgt, kgt, vgn, hgt);
  k6_hp_proj   <<<dim3(NB*1024),  dim3(256), 0, stream>>>(vnat, P, hgt, pw, x, out);
}